// Round 3
// baseline (836.405 us; speedup 1.0000x reference)
//
#include <hip/hip_runtime.h>
#include <hip/hip_bf16.h>
#include <cstdint>

// MultiViewGAT: N=8192, F=128. Round 3: BARRIER-FREE MFMA attention.
// k2 computes A-fragments (P = masked exp of rank-1 scores) directly in
// registers in MFMA A-layout (lane = row lpos, k-octet halfk*8..+8), and
// loads B-fragments straight from bf16 Whbt[ch][j] (16B/lane, L2-resident
// 4 MB). No LDS, no __syncthreads -> no vmcnt(0) barrier drains; adj HBM
// streaming (512 MB) is the floor (~85 us). Denominator = VALU row-sum of
// the fp32 P values + shfl_xor reduce (bf16-vs-fp32 sum mismatch averages
// out over ~2458 terms; well under the 0.1 threshold).

#define N 8192
#define F 128
#define JS 8      // j-splits; partials reduced in k4; grid = 64*2*8 = 1024

typedef __attribute__((ext_vector_type(8))) short short8;
typedef __attribute__((ext_vector_type(8))) unsigned short ushort8;
typedef __attribute__((ext_vector_type(4))) float floatx4;

__device__ inline unsigned int f2bf(float x) {
  unsigned int u = __float_as_uint(x);
  u += 0x7FFFu + ((u >> 16) & 1u);   // RNE
  return u >> 16;
}

// ws layout (float elements):
//   Whbt  [2][F][N] bf16    @ 0           (1,048,576 float slots = 4 MB)
//   hpart [2][JS][N][F]     @ 1,048,576   (16,777,216)
//   f1    [2][N]            @ 17,825,792  (16,384)
//   f2    [2][N]            @ 17,842,176  (16,384)
//   Lpart [2][JS][N]        @ 17,858,560  (131,072)
//   qln   [F]               @ 17,989,632  (128)
// total ~72 MB

// ---------------- K1: Wh = X @ W; emit bf16 Whbt (transposed) + f1/f2 -------
__global__ __launch_bounds__(128) void k1_wh(
    const float* __restrict__ X2, const float* __restrict__ W0,
    const float* __restrict__ W1, const float* __restrict__ a0,
    const float* __restrict__ a1, unsigned short* __restrict__ Whbt,
    float* __restrict__ f1g, float* __restrict__ f2g) {
  const int l  = blockIdx.y;
  const int i0 = blockIdx.x * 16;
  const int c  = threadIdx.x;
  const float* __restrict__ X = X2 + (size_t)l * N * F + (size_t)i0 * F;
  const float* __restrict__ W = l ? W1 : W0;

  __shared__ __align__(16) float sX[16 * F];
  __shared__ float red[2][2][16];
  {
    const float4* src = (const float4*)X;
    float4* dst = (float4*)sX;
#pragma unroll
    for (int qq = 0; qq < 4; ++qq) dst[qq * 128 + c] = src[qq * 128 + c];
  }
  __syncthreads();

  float acc[16];
#pragma unroll
  for (int r = 0; r < 16; ++r) acc[r] = 0.f;

  for (int f4 = 0; f4 < 32; ++f4) {
    float w0 = W[(f4 * 4 + 0) * F + c];
    float w1 = W[(f4 * 4 + 1) * F + c];
    float w2 = W[(f4 * 4 + 2) * F + c];
    float w3 = W[(f4 * 4 + 3) * F + c];
#pragma unroll
    for (int r = 0; r < 16; ++r) {
      float4 xv = *(const float4*)(&sX[r * F + f4 * 4]);
      acc[r] = fmaf(xv.x, w0, acc[r]);
      acc[r] = fmaf(xv.y, w1, acc[r]);
      acc[r] = fmaf(xv.z, w2, acc[r]);
      acc[r] = fmaf(xv.w, w3, acc[r]);
    }
  }

  // Whbt[l][c][i0..i0+16) bf16
  {
    unsigned short* wdst = Whbt + (size_t)l * F * N + (size_t)c * N + i0;
    ushort8 u0, u1;
#pragma unroll
    for (int r = 0; r < 8; ++r) {
      u0[r] = (unsigned short)f2bf(acc[r]);
      u1[r] = (unsigned short)f2bf(acc[8 + r]);
    }
    *(ushort8*)wdst = u0;
    *(ushort8*)(wdst + 8) = u1;
  }

  // f1/f2: reduce acc[r]*a[c] over 128 channels
  const float* __restrict__ a = l ? a1 : a0;
  const float a1c = a[c], a2c = a[F + c];
  const int w = c >> 6, lane = c & 63;
#pragma unroll
  for (int r = 0; r < 16; ++r) {
    float s1 = acc[r] * a1c;
    float s2 = acc[r] * a2c;
#pragma unroll
    for (int off = 32; off; off >>= 1) {
      s1 += __shfl_down(s1, off);
      s2 += __shfl_down(s2, off);
    }
    if (lane == 0) {
      red[w][0][r] = s1;
      red[w][1][r] = s2;
    }
  }
  __syncthreads();
  if (c < 16)
    f1g[l * N + i0 + c] = red[0][0][c] + red[1][0][c];
  else if (c < 32)
    f2g[l * N + i0 + c - 16] = red[0][1][c - 16] + red[1][1][c - 16];
}

// ---------------- K3: layernorm of query [1,F] ----------------
__global__ __launch_bounds__(128) void k3_qln(
    const float* __restrict__ query, const float* __restrict__ gamma,
    const float* __restrict__ beta, float* __restrict__ qln) {
  const int t = threadIdx.x;
  float v = query[t];
  float s = v, sq = v * v;
#pragma unroll
  for (int off = 32; off; off >>= 1) {
    s += __shfl_down(s, off);
    sq += __shfl_down(sq, off);
  }
  __shared__ float sb[4];
  if ((t & 63) == 0) {
    sb[t >> 6] = s;
    sb[2 + (t >> 6)] = sq;
  }
  __syncthreads();
  float S = sb[0] + sb[1], SQ = sb[2] + sb[3];
  float mu = S * (1.f / 128.f);
  float var = SQ * (1.f / 128.f) - mu * mu;
  qln[t] = (v - mu) * rsqrtf(var + 1e-5f) * gamma[t] + beta[t];
}

// ---------------- K2: barrier-free MFMA masked-softmax attention -------------
// Per block: 128 i-rows x 128 channels over j-range N/JS. Per wave: rows
// wave*32..+31 (two 16-row MFMA tiles). A-frag computed in-register, B-frag
// loaded direct from Whbt (L2). Zero LDS, zero barriers.
__device__ inline short8 make_pfrag(float f1v, const float4& fa,
                                    const float4& fb, const int4& a0,
                                    const int4& a1, float& Lacc) {
  float p0, p1, p2, p3, p4, p5, p6, p7, sc;
  sc = f1v + fa.x; sc = fmaxf(sc, 0.2f * sc); p0 = a0.x ? __expf(sc) : 0.f;
  sc = f1v + fa.y; sc = fmaxf(sc, 0.2f * sc); p1 = a0.y ? __expf(sc) : 0.f;
  sc = f1v + fa.z; sc = fmaxf(sc, 0.2f * sc); p2 = a0.z ? __expf(sc) : 0.f;
  sc = f1v + fa.w; sc = fmaxf(sc, 0.2f * sc); p3 = a0.w ? __expf(sc) : 0.f;
  sc = f1v + fb.x; sc = fmaxf(sc, 0.2f * sc); p4 = a1.x ? __expf(sc) : 0.f;
  sc = f1v + fb.y; sc = fmaxf(sc, 0.2f * sc); p5 = a1.y ? __expf(sc) : 0.f;
  sc = f1v + fb.z; sc = fmaxf(sc, 0.2f * sc); p6 = a1.z ? __expf(sc) : 0.f;
  sc = f1v + fb.w; sc = fmaxf(sc, 0.2f * sc); p7 = a1.w ? __expf(sc) : 0.f;
  Lacc += ((p0 + p1) + (p2 + p3)) + ((p4 + p5) + (p6 + p7));
  union { unsigned int u[4]; short8 s8; } r;
  r.u[0] = f2bf(p0) | (f2bf(p1) << 16);
  r.u[1] = f2bf(p2) | (f2bf(p3) << 16);
  r.u[2] = f2bf(p4) | (f2bf(p5) << 16);
  r.u[3] = f2bf(p6) | (f2bf(p7) << 16);
  return r.s8;
}

__global__ __launch_bounds__(256) void k2_attn(
    const unsigned short* __restrict__ Whbt, const float* __restrict__ f1g,
    const float* __restrict__ f2g, const int* __restrict__ adj,
    float* __restrict__ hpart, float* __restrict__ Lpart) {
  const int l  = blockIdx.y;
  const int s  = blockIdx.z;
  const int i0 = blockIdx.x * 128;
  const int t  = threadIdx.x;
  const int wave = t >> 6, lane = t & 63;
  const int lpos = lane & 15, halfk = lane >> 4;

  const unsigned short* __restrict__ WhbL = Whbt + (size_t)l * F * N;
  const int* __restrict__ adjL = adj + (size_t)l * N * N;
  const float* __restrict__ f2L = f2g + l * N;

  const int rowA = i0 + wave * 32 + lpos;        // mt=0 row
  const float f1a = f1g[l * N + rowA];
  const float f1b = f1g[l * N + rowA + 16];      // mt=1 row
  const int* __restrict__ adjA = adjL + (size_t)rowA * N + halfk * 8;
  const int* __restrict__ adjB = adjA + (size_t)16 * N;
  const unsigned short* __restrict__ bbase = WhbL + (size_t)lpos * N + halfk * 8;
  const float* __restrict__ f2base = f2L + halfk * 8;

  floatx4 acc[2][8];
#pragma unroll
  for (int mt = 0; mt < 2; ++mt)
#pragma unroll
    for (int nt = 0; nt < 8; ++nt) acc[mt][nt] = (floatx4){0.f, 0.f, 0.f, 0.f};
  float Lacc0 = 0.f, Lacc1 = 0.f;

  const int jbeg = s * (N / JS);
  for (int jj = 0; jj < N / JS; jj += 32) {
    const int j0 = jbeg + jj;
    // issue adj (HBM) first, then f2 (L1/L2), then B (L2): the compiler's
    // vmcnt waits for P-compute leave the later B loads in flight.
    int4 a0 = *(const int4*)(adjA + j0);
    int4 a1 = *(const int4*)(adjA + j0 + 4);
    int4 b0 = *(const int4*)(adjB + j0);
    int4 b1 = *(const int4*)(adjB + j0 + 4);
    float4 fa = *(const float4*)(f2base + j0);
    float4 fb = *(const float4*)(f2base + j0 + 4);
    short8 bfv[8];
#pragma unroll
    for (int nt = 0; nt < 8; ++nt)
      bfv[nt] = *(const short8*)(bbase + (size_t)nt * 16 * N + j0);

    short8 af0 = make_pfrag(f1a, fa, fb, a0, a1, Lacc0);
    short8 af1 = make_pfrag(f1b, fa, fb, b0, b1, Lacc1);

#pragma unroll
    for (int nt = 0; nt < 8; ++nt) {
      acc[0][nt] = __builtin_amdgcn_mfma_f32_16x16x32_bf16(af0, bfv[nt], acc[0][nt], 0, 0, 0);
      acc[1][nt] = __builtin_amdgcn_mfma_f32_16x16x32_bf16(af1, bfv[nt], acc[1][nt], 0, 0, 0);
    }
  }

  // ---- epilogue: partial numerator + partial denominators ----
  const size_t obase = ((size_t)(l * JS + s) * N + i0) * F;
  const size_t lbase = (size_t)(l * JS + s) * N + i0;
#pragma unroll
  for (int mt = 0; mt < 2; ++mt) {
    const int rb = wave * 32 + mt * 16 + halfk * 4;  // C/D: row=(lane>>4)*4+reg
#pragma unroll
    for (int nt = 0; nt < 8; ++nt) {
#pragma unroll
      for (int reg = 0; reg < 4; ++reg)
        hpart[obase + (size_t)(rb + reg) * F + nt * 16 + lpos] = acc[mt][nt][reg];
    }
  }
  // denominator: reduce across halfk groups (lanes lpos, +16, +32, +48)
  Lacc0 += __shfl_xor(Lacc0, 16);
  Lacc0 += __shfl_xor(Lacc0, 32);
  Lacc1 += __shfl_xor(Lacc1, 16);
  Lacc1 += __shfl_xor(Lacc1, 32);
  if (halfk == 0) {
    Lpart[lbase + wave * 32 + lpos] = Lacc0;
    Lpart[lbase + wave * 32 + 16 + lpos] = Lacc1;
  }
}

// ---------------- K4: combine partials, query attention, mix, residual -------
// one wave per row; 2 channels per lane; shuffle-only reductions.
__global__ __launch_bounds__(256) void k4_mix(
    const float* __restrict__ hpart, const float* __restrict__ Lpart,
    const float* __restrict__ MPNN, const float* __restrict__ qln,
    const float* __restrict__ x0, const float* __restrict__ res,
    float* __restrict__ out) {
  const int row  = blockIdx.x * 4 + (threadIdx.x >> 6);
  const int lane = threadIdx.x & 63;
  const int c    = lane * 2;

  float h0x = 0.f, h0y = 0.f, h1x = 0.f, h1y = 0.f, L0 = 0.f, L1 = 0.f;
#pragma unroll
  for (int sx = 0; sx < JS; ++sx) {
    float2 v0 = *(const float2*)&hpart[((size_t)(0 * JS + sx) * N + row) * F + c];
    float2 v1 = *(const float2*)&hpart[((size_t)(1 * JS + sx) * N + row) * F + c];
    h0x += v0.x; h0y += v0.y;
    h1x += v1.x; h1y += v1.y;
    L0 += Lpart[(size_t)(0 * JS + sx) * N + row];
    L1 += Lpart[(size_t)(1 * JS + sx) * N + row];
  }
  const float i0v = 1.f / L0, i1v = 1.f / L1;
  h0x *= i0v; h0y *= i0v;
  h1x *= i1v; h1y *= i1v;

  float2 mv = *(const float2*)&MPNN[(size_t)row * F + c];
  float2 qv = *(const float2*)&qln[c];
  float w1 = qv.x * h0x + qv.y * h0y;
  float w2 = qv.x * h1x + qv.y * h1y;
  float w3 = qv.x * mv.x + qv.y * mv.y;
#pragma unroll
  for (int off = 1; off < 64; off <<= 1) {
    w1 += __shfl_xor(w1, off);
    w2 += __shfl_xor(w2, off);
    w3 += __shfl_xor(w3, off);
  }
  float m = fmaxf(w1, fmaxf(w2, w3));
  float e1 = __expf(w1 - m), e2 = __expf(w2 - m), e3 = __expf(w3 - m);
  float inv = res[0] / (e1 + e2 + e3);
  float2 xr = *(const float2*)&x0[(size_t)row * F + c];
  float2 o;
  o.x = (e1 * h0x + e2 * h1x + e3 * mv.x) * inv + xr.x;
  o.y = (e1 * h0y + e2 * h1y + e3 * mv.y) * inv + xr.y;
  *(float2*)&out[(size_t)row * F + c] = o;
}

extern "C" void kernel_launch(void* const* d_in, const int* in_sizes, int n_in,
                              void* d_out, int out_size, void* d_ws,
                              size_t ws_size, hipStream_t stream) {
  const float* x2    = (const float*)d_in[0];   // input_hs [2][N][F]
  const int*   adj   = (const int*)d_in[1];     // adjs [2][N][N] (bool->int32)
  const float* mpnn  = (const float*)d_in[2];   // [N][F]
  const float* query = (const float*)d_in[3];   // [1][F]
  const float* W0    = (const float*)d_in[4];
  const float* a0    = (const float*)d_in[5];
  const float* W1    = (const float*)d_in[6];
  const float* a1    = (const float*)d_in[7];
  const float* gamma = (const float*)d_in[8];
  const float* beta  = (const float*)d_in[9];
  const float* res   = (const float*)d_in[10];  // [1][1]

  float* ws = (float*)d_ws;
  unsigned short* Whbt = (unsigned short*)ws;        // 4 MB
  float* hpart = ws + 1048576;
  float* f1g   = ws + 17825792;
  float* f2g   = ws + 17842176;
  float* Lpart = ws + 17858560;
  float* qln   = ws + 17989632;
  float* out   = (float*)d_out;

  k1_wh<<<dim3(N / 16, 2), 128, 0, stream>>>(x2, W0, W1, a0, a1, Whbt, f1g, f2g);
  k3_qln<<<1, 128, 0, stream>>>(query, gamma, beta, qln);
  k2_attn<<<dim3(N / 128, 2, JS), 256, 0, stream>>>(Whbt, f1g, f2g, adj, hpart,
                                                    Lpart);
  k4_mix<<<N / 4, 256, 0, stream>>>(hpart, Lpart, mpnn, qln, x2, res, out);
}

// Round 4
// 816.526 us; speedup vs baseline: 1.0243x; 1.0243x over previous
//
#include <hip/hip_runtime.h>
#include <hip/hip_bf16.h>
#include <cstdint>

// MultiViewGAT: N=8192, F=128. Round 4: hybrid MFMA attention.
// - A-frags (P = masked exp of rank-1 scores) computed in registers in MFMA
//   A-layout (lane row = lpos, k-octet = halfk*8). adj int32 read directly
//   (HBM stream, the 512 MB floor), software-prefetched one 32-j tile ahead.
// - B-frags (bf16 Wh^T) staged through LDS in 128-j super-tiles: coalesced
//   global loads once per 4 inner iters, then conflict-free ds_read_b128
//   (row stride 136 shorts = 272 B == 4 banks shift -> 2-way, free).
// - Barriers: 2 per 128-j stage (16 per block) vs 2 per 32-j in R2 (128).
// - Denominator: VALU row-sum of fp32 P + shfl_xor across halfk lanes.

#define N 8192
#define F 128
#define JS 8      // j-splits; grid = 64 x 2 x 8 = 1024 blocks (~4/CU)

typedef __attribute__((ext_vector_type(8))) short short8;
typedef __attribute__((ext_vector_type(8))) unsigned short ushort8;
typedef __attribute__((ext_vector_type(4))) float floatx4;

__device__ inline unsigned int f2bf(float x) {
  unsigned int u = __float_as_uint(x);
  u += 0x7FFFu + ((u >> 16) & 1u);   // RNE
  return u >> 16;
}

// ws layout (float elements):
//   Whbt  [2][F][N] bf16    @ 0           (1,048,576 float slots = 4 MB)
//   hpart [2][JS][N][F]     @ 1,048,576   (16,777,216)
//   f1    [2][N]            @ 17,825,792  (16,384)
//   f2    [2][N]            @ 17,842,176  (16,384)
//   Lpart [2][JS][N]        @ 17,858,560  (131,072)
//   qln   [F]               @ 17,989,632  (128)

// ---------------- K1: Wh = X @ W; emit bf16 Whbt (transposed) + f1/f2 -------
__global__ __launch_bounds__(128) void k1_wh(
    const float* __restrict__ X2, const float* __restrict__ W0,
    const float* __restrict__ W1, const float* __restrict__ a0,
    const float* __restrict__ a1, unsigned short* __restrict__ Whbt,
    float* __restrict__ f1g, float* __restrict__ f2g) {
  const int l  = blockIdx.y;
  const int i0 = blockIdx.x * 16;
  const int c  = threadIdx.x;
  const float* __restrict__ X = X2 + (size_t)l * N * F + (size_t)i0 * F;
  const float* __restrict__ W = l ? W1 : W0;

  __shared__ __align__(16) float sX[16 * F];
  __shared__ float red[2][2][16];
  {
    const float4* src = (const float4*)X;
    float4* dst = (float4*)sX;
#pragma unroll
    for (int qq = 0; qq < 4; ++qq) dst[qq * 128 + c] = src[qq * 128 + c];
  }
  __syncthreads();

  float acc[16];
#pragma unroll
  for (int r = 0; r < 16; ++r) acc[r] = 0.f;

  for (int f4 = 0; f4 < 32; ++f4) {
    float w0 = W[(f4 * 4 + 0) * F + c];
    float w1 = W[(f4 * 4 + 1) * F + c];
    float w2 = W[(f4 * 4 + 2) * F + c];
    float w3 = W[(f4 * 4 + 3) * F + c];
#pragma unroll
    for (int r = 0; r < 16; ++r) {
      float4 xv = *(const float4*)(&sX[r * F + f4 * 4]);
      acc[r] = fmaf(xv.x, w0, acc[r]);
      acc[r] = fmaf(xv.y, w1, acc[r]);
      acc[r] = fmaf(xv.z, w2, acc[r]);
      acc[r] = fmaf(xv.w, w3, acc[r]);
    }
  }

  {
    unsigned short* wdst = Whbt + (size_t)l * F * N + (size_t)c * N + i0;
    ushort8 u0, u1;
#pragma unroll
    for (int r = 0; r < 8; ++r) {
      u0[r] = (unsigned short)f2bf(acc[r]);
      u1[r] = (unsigned short)f2bf(acc[8 + r]);
    }
    *(ushort8*)wdst = u0;
    *(ushort8*)(wdst + 8) = u1;
  }

  const float* __restrict__ a = l ? a1 : a0;
  const float a1c = a[c], a2c = a[F + c];
  const int w = c >> 6, lane = c & 63;
#pragma unroll
  for (int r = 0; r < 16; ++r) {
    float s1 = acc[r] * a1c;
    float s2 = acc[r] * a2c;
#pragma unroll
    for (int off = 32; off; off >>= 1) {
      s1 += __shfl_down(s1, off);
      s2 += __shfl_down(s2, off);
    }
    if (lane == 0) {
      red[w][0][r] = s1;
      red[w][1][r] = s2;
    }
  }
  __syncthreads();
  if (c < 16)
    f1g[l * N + i0 + c] = red[0][0][c] + red[1][0][c];
  else if (c < 32)
    f2g[l * N + i0 + c - 16] = red[0][1][c - 16] + red[1][1][c - 16];
}

// ---------------- K3: layernorm of query [1,F] ----------------
__global__ __launch_bounds__(128) void k3_qln(
    const float* __restrict__ query, const float* __restrict__ gamma,
    const float* __restrict__ beta, float* __restrict__ qln) {
  const int t = threadIdx.x;
  float v = query[t];
  float s = v, sq = v * v;
#pragma unroll
  for (int off = 32; off; off >>= 1) {
    s += __shfl_down(s, off);
    sq += __shfl_down(sq, off);
  }
  __shared__ float sb[4];
  if ((t & 63) == 0) {
    sb[t >> 6] = s;
    sb[2 + (t >> 6)] = sq;
  }
  __syncthreads();
  float S = sb[0] + sb[1], SQ = sb[2] + sb[3];
  float mu = S * (1.f / 128.f);
  float var = SQ * (1.f / 128.f) - mu * mu;
  qln[t] = (v - mu) * rsqrtf(var + 1e-5f) * gamma[t] + beta[t];
}

// ---------------- K2: hybrid MFMA masked-softmax attention -------------------
__device__ inline short8 make_pfrag(float f1v, const float4& fa,
                                    const float4& fb, const int4& a0,
                                    const int4& a1, float& Lacc) {
  float p0, p1, p2, p3, p4, p5, p6, p7, sc;
  sc = f1v + fa.x; sc = fmaxf(sc, 0.2f * sc); p0 = a0.x ? __expf(sc) : 0.f;
  sc = f1v + fa.y; sc = fmaxf(sc, 0.2f * sc); p1 = a0.y ? __expf(sc) : 0.f;
  sc = f1v + fa.z; sc = fmaxf(sc, 0.2f * sc); p2 = a0.z ? __expf(sc) : 0.f;
  sc = f1v + fa.w; sc = fmaxf(sc, 0.2f * sc); p3 = a0.w ? __expf(sc) : 0.f;
  sc = f1v + fb.x; sc = fmaxf(sc, 0.2f * sc); p4 = a1.x ? __expf(sc) : 0.f;
  sc = f1v + fb.y; sc = fmaxf(sc, 0.2f * sc); p5 = a1.y ? __expf(sc) : 0.f;
  sc = f1v + fb.z; sc = fmaxf(sc, 0.2f * sc); p6 = a1.z ? __expf(sc) : 0.f;
  sc = f1v + fb.w; sc = fmaxf(sc, 0.2f * sc); p7 = a1.w ? __expf(sc) : 0.f;
  Lacc += ((p0 + p1) + (p2 + p3)) + ((p4 + p5) + (p6 + p7));
  union { unsigned int u[4]; short8 s8; } r;
  r.u[0] = f2bf(p0) | (f2bf(p1) << 16);
  r.u[1] = f2bf(p2) | (f2bf(p3) << 16);
  r.u[2] = f2bf(p4) | (f2bf(p5) << 16);
  r.u[3] = f2bf(p6) | (f2bf(p7) << 16);
  return r.s8;
}

__global__ __launch_bounds__(256) void k2_attn(
    const unsigned short* __restrict__ Whbt, const float* __restrict__ f1g,
    const float* __restrict__ f2g, const int* __restrict__ adj,
    float* __restrict__ hpart, float* __restrict__ Lpart) {
  const int l  = blockIdx.y;
  const int s  = blockIdx.z;
  const int i0 = blockIdx.x * 128;
  const int t  = threadIdx.x;
  const int wave = t >> 6, lane = t & 63;
  const int lpos = lane & 15, halfk = lane >> 4;

  // B super-tile: 128 ch x 128 j, row stride 136 shorts (272 B = 4-bank shift)
  __shared__ __align__(16) unsigned short sB[128][136];   // 34.8 KB

  const unsigned short* __restrict__ WhbL = Whbt + (size_t)l * F * N;
  const int* __restrict__ adjL = adj + (size_t)l * N * N;
  const float* __restrict__ f2L = f2g + l * N;

  const int rowA = i0 + wave * 32 + lpos;
  const float f1a = f1g[l * N + rowA];
  const float f1b = f1g[l * N + rowA + 16];
  const int* __restrict__ adjA = adjL + (size_t)rowA * N + halfk * 8;
  const int* __restrict__ adjB = adjA + (size_t)16 * N;
  const float* __restrict__ f2base = f2L + halfk * 8;

  // staging addresses: thread t covers ch = t>>1, 8 x 16B segs
  const unsigned short* __restrict__ wsrc = WhbL + (size_t)(t >> 1) * N + (t & 1) * 8;
  unsigned short* __restrict__ sdst = &sB[t >> 1][(t & 1) * 8];

  floatx4 acc[2][8];
#pragma unroll
  for (int mt = 0; mt < 2; ++mt)
#pragma unroll
    for (int nt = 0; nt < 8; ++nt) acc[mt][nt] = (floatx4){0.f, 0.f, 0.f, 0.f};
  float Lacc0 = 0.f, Lacc1 = 0.f;

  const int jbeg = s * (N / JS);

  // prefetch adj for the first 32-j tile
  int4 ca0 = *(const int4*)(adjA + jbeg);
  int4 ca1 = *(const int4*)(adjA + jbeg + 4);
  int4 cb0 = *(const int4*)(adjB + jbeg);
  int4 cb1 = *(const int4*)(adjB + jbeg + 4);

  for (int st = 0; st < (N / JS) / 128; ++st) {   // 8 stages
    const int jb = jbeg + st * 128;
    __syncthreads();   // previous stage's ds_reads done before overwrite
#pragma unroll
    for (int r = 0; r < 8; ++r)
      *(uint4*)(sdst + r * 16) = *(const uint4*)(wsrc + jb + r * 16);
    __syncthreads();

#pragma unroll
    for (int s4 = 0; s4 < 4; ++s4) {
      const int j0 = jb + s4 * 32;
      int jn = j0 + 32;
      if (jn >= jbeg + (N / JS)) jn = jbeg;   // last tile: dummy (discarded)
      // prefetch next tile's adj (HBM) before consuming current regs
      int4 na0 = *(const int4*)(adjA + jn);
      int4 na1 = *(const int4*)(adjA + jn + 4);
      int4 nb0 = *(const int4*)(adjB + jn);
      int4 nb1 = *(const int4*)(adjB + jn + 4);
      float4 fa = *(const float4*)(f2base + j0);
      float4 fb = *(const float4*)(f2base + j0 + 4);

      short8 af0 = make_pfrag(f1a, fa, fb, ca0, ca1, Lacc0);
      short8 af1 = make_pfrag(f1b, fa, fb, cb0, cb1, Lacc1);

      const unsigned short* bp = &sB[lpos][s4 * 32 + halfk * 8];
#pragma unroll
      for (int nt = 0; nt < 8; ++nt) {
        short8 bf = *(const short8*)(bp + nt * 16 * 136);
        acc[0][nt] = __builtin_amdgcn_mfma_f32_16x16x32_bf16(af0, bf, acc[0][nt], 0, 0, 0);
        acc[1][nt] = __builtin_amdgcn_mfma_f32_16x16x32_bf16(af1, bf, acc[1][nt], 0, 0, 0);
      }
      ca0 = na0; ca1 = na1; cb0 = nb0; cb1 = nb1;
    }
  }

  // ---- epilogue: partial numerator + partial denominators ----
  const size_t obase = ((size_t)(l * JS + s) * N + i0) * F;
  const size_t lbase = (size_t)(l * JS + s) * N + i0;
#pragma unroll
  for (int mt = 0; mt < 2; ++mt) {
    const int rb = wave * 32 + mt * 16 + halfk * 4;  // C/D: row=(lane>>4)*4+reg
#pragma unroll
    for (int nt = 0; nt < 8; ++nt) {
#pragma unroll
      for (int reg = 0; reg < 4; ++reg)
        hpart[obase + (size_t)(rb + reg) * F + nt * 16 + lpos] = acc[mt][nt][reg];
    }
  }
  Lacc0 += __shfl_xor(Lacc0, 16);
  Lacc0 += __shfl_xor(Lacc0, 32);
  Lacc1 += __shfl_xor(Lacc1, 16);
  Lacc1 += __shfl_xor(Lacc1, 32);
  if (halfk == 0) {
    Lpart[lbase + wave * 32 + lpos] = Lacc0;
    Lpart[lbase + wave * 32 + 16 + lpos] = Lacc1;
  }
}

// ---------------- K4: combine partials, query attention, mix, residual -------
__global__ __launch_bounds__(256) void k4_mix(
    const float* __restrict__ hpart, const float* __restrict__ Lpart,
    const float* __restrict__ MPNN, const float* __restrict__ qln,
    const float* __restrict__ x0, const float* __restrict__ res,
    float* __restrict__ out) {
  const int row  = blockIdx.x * 4 + (threadIdx.x >> 6);
  const int lane = threadIdx.x & 63;
  const int c    = lane * 2;

  float h0x = 0.f, h0y = 0.f, h1x = 0.f, h1y = 0.f, L0 = 0.f, L1 = 0.f;
#pragma unroll
  for (int sx = 0; sx < JS; ++sx) {
    float2 v0 = *(const float2*)&hpart[((size_t)(0 * JS + sx) * N + row) * F + c];
    float2 v1 = *(const float2*)&hpart[((size_t)(1 * JS + sx) * N + row) * F + c];
    h0x += v0.x; h0y += v0.y;
    h1x += v1.x; h1y += v1.y;
    L0 += Lpart[(size_t)(0 * JS + sx) * N + row];
    L1 += Lpart[(size_t)(1 * JS + sx) * N + row];
  }
  const float i0v = 1.f / L0, i1v = 1.f / L1;
  h0x *= i0v; h0y *= i0v;
  h1x *= i1v; h1y *= i1v;

  float2 mv = *(const float2*)&MPNN[(size_t)row * F + c];
  float2 qv = *(const float2*)&qln[c];
  float w1 = qv.x * h0x + qv.y * h0y;
  float w2 = qv.x * h1x + qv.y * h1y;
  float w3 = qv.x * mv.x + qv.y * mv.y;
#pragma unroll
  for (int off = 1; off < 64; off <<= 1) {
    w1 += __shfl_xor(w1, off);
    w2 += __shfl_xor(w2, off);
    w3 += __shfl_xor(w3, off);
  }
  float m = fmaxf(w1, fmaxf(w2, w3));
  float e1 = __expf(w1 - m), e2 = __expf(w2 - m), e3 = __expf(w3 - m);
  float inv = res[0] / (e1 + e2 + e3);
  float2 xr = *(const float2*)&x0[(size_t)row * F + c];
  float2 o;
  o.x = (e1 * h0x + e2 * h1x + e3 * mv.x) * inv + xr.x;
  o.y = (e1 * h0y + e2 * h1y + e3 * mv.y) * inv + xr.y;
  *(float2*)&out[(size_t)row * F + c] = o;
}

extern "C" void kernel_launch(void* const* d_in, const int* in_sizes, int n_in,
                              void* d_out, int out_size, void* d_ws,
                              size_t ws_size, hipStream_t stream) {
  const float* x2    = (const float*)d_in[0];   // input_hs [2][N][F]
  const int*   adj   = (const int*)d_in[1];     // adjs [2][N][N] (bool->int32)
  const float* mpnn  = (const float*)d_in[2];   // [N][F]
  const float* query = (const float*)d_in[3];   // [1][F]
  const float* W0    = (const float*)d_in[4];
  const float* a0    = (const float*)d_in[5];
  const float* W1    = (const float*)d_in[6];
  const float* a1    = (const float*)d_in[7];
  const float* gamma = (const float*)d_in[8];
  const float* beta  = (const float*)d_in[9];
  const float* res   = (const float*)d_in[10];  // [1][1]

  float* ws = (float*)d_ws;
  unsigned short* Whbt = (unsigned short*)ws;        // 4 MB
  float* hpart = ws + 1048576;
  float* f1g   = ws + 17825792;
  float* f2g   = ws + 17842176;
  float* Lpart = ws + 17858560;
  float* qln   = ws + 17989632;
  float* out   = (float*)d_out;

  k1_wh<<<dim3(N / 16, 2), 128, 0, stream>>>(x2, W0, W1, a0, a1, Whbt, f1g, f2g);
  k3_qln<<<1, 128, 0, stream>>>(query, gamma, beta, qln);
  k2_attn<<<dim3(N / 128, 2, JS), 256, 0, stream>>>(Whbt, f1g, f2g, adj, hpart,
                                                    Lpart);
  k4_mix<<<N / 4, 256, 0, stream>>>(hpart, Lpart, mpnn, qln, x2, res, out);
}